// Round 4
// baseline (2283.509 us; speedup 1.0000x reference)
//
#include <hip/hip_runtime.h>
#include <cstdint>
#include <cstddef>

#define N_POS 196

// ---------------- 1x1 conv (channel matmul) + folded BatchNorm ----------------
// X: (ntb, CIN, 196)  W: (Cout, CIN)  Y: (ntb, Cout, 196)
// Per block: one tb, 64 output channels, all 196 positions. K staged in LDS chunks of 32.
// tb mapping: l = blockIdx.x in [0, 4*nb); global tb = (l/nb)*32 + b0 + l%nb.
// xlocal/ylocal select chunk-local (l) vs global (mapped) indexing for X/Y.
// USE_FMA=false replicates a sequential mul-then-add reduction (continuous
// inputs); USE_FMA=true is bitwise-identical for binary {0,1} inputs (products
// are exact) and faster. ACCUM adds the result into Y (fused residual).
template<int CIN, bool USE_FMA, bool ACCUM>
__global__ __launch_bounds__(512) void convbn_kernel(
    const float* __restrict__ X, const float* __restrict__ W,
    const float* __restrict__ Bi, const float* __restrict__ Ga,
    const float* __restrict__ Be, const float* __restrict__ Mu,
    const float* __restrict__ Va, float* __restrict__ Y, int Cout,
    int nb, int b0, int xlocal, int ylocal)
{
    __shared__ float Xs[32][200];   // 32 K-rows x 196 positions (+pad, cols 196..199 zeroed)
    __shared__ float Ws[32][68];    // 32 K-rows x 64 outputs (+pad)
    const int tid = threadIdx.x;
    const int l   = blockIdx.x;
    const int t   = l / nb;
    const int bl  = l - t * nb;
    const int tbg = t * 32 + b0 + bl;
    const int xtb = xlocal ? l : tbg;
    const int ytb = ylocal ? l : tbg;
    const int o0  = blockIdx.y * 64;
    const int n0  = tid & 63;                 // position within 64-chunk
    const int obase = (tid >> 6) * 8;         // 8 consecutive outputs per thread
    const int col3 = (n0 < 4) ? (n0 + 192) : 196;  // col 196 is zeroed -> harmless
    float acc[8][4];
    #pragma unroll
    for (int i = 0; i < 8; ++i)
        #pragma unroll
        for (int j = 0; j < 4; ++j) acc[i][j] = 0.f;
    if (tid < 128) { Xs[tid >> 2][196 + (tid & 3)] = 0.f; }
    const float* Xtb = X + (size_t)xtb * CIN * N_POS;
    const float* Wp  = W + (size_t)o0 * CIN;

    for (int kc = 0; kc < CIN; kc += 32) {
        // stage X chunk: 32 x 196 as 1568 float4s
        for (int i = tid; i < 1568; i += 512) {
            int r = i / 49, c4 = i - r * 49;
            *(float4*)&Xs[r][c4 * 4] =
                *(const float4*)(Xtb + (size_t)(kc + r) * N_POS + c4 * 4);
        }
        // stage W chunk: 64 outputs x 32 k, one float4 per thread
        {
            int oo = tid >> 3, k4 = tid & 7;
            float4 w = *(const float4*)(Wp + (size_t)oo * CIN + kc + k4 * 4);
            Ws[k4 * 4 + 0][oo] = w.x; Ws[k4 * 4 + 1][oo] = w.y;
            Ws[k4 * 4 + 2][oo] = w.z; Ws[k4 * 4 + 3][oo] = w.w;
        }
        __syncthreads();
        #pragma unroll 4
        for (int kk = 0; kk < 32; ++kk) {
            float4 wA = *(const float4*)&Ws[kk][obase];      // wave-uniform broadcast
            float4 wB = *(const float4*)&Ws[kk][obase + 4];
            float xv[4] = { Xs[kk][n0], Xs[kk][n0 + 64], Xs[kk][n0 + 128], Xs[kk][col3] };
            float wv[8] = { wA.x, wA.y, wA.z, wA.w, wB.x, wB.y, wB.z, wB.w };
            #pragma unroll
            for (int i = 0; i < 8; ++i)
                #pragma unroll
                for (int j = 0; j < 4; ++j) {
                    if (USE_FMA) acc[i][j] = fmaf(wv[i], xv[j], acc[i][j]);
                    else         acc[i][j] = __fadd_rn(acc[i][j], __fmul_rn(wv[i], xv[j]));
                }
        }
        __syncthreads();
    }
    #pragma unroll
    for (int i = 0; i < 8; ++i) {
        int o = o0 + obase + i;
        // match reference op-for-op: inv = g*rsqrt(var+eps); y = conv (+ bias);
        // r = y*inv + (beta - m*inv)
        float sc = __fmul_rn(Ga[o], 1.0f / sqrtf(__fadd_rn(Va[o], 1e-5f)));
        float sh = __fsub_rn(Be[o], __fmul_rn(Mu[o], sc));
        float* yp = Y + ((size_t)ytb * Cout + o) * N_POS;
        #pragma unroll
        for (int j = 0; j < 4; ++j) {
            if (j == 3 && n0 >= 4) continue;
            float y = acc[i][j];
            if (Bi) y = __fadd_rn(y, Bi[o]);
            float r = __fadd_rn(__fmul_rn(y, sc), sh);
            int n = n0 + j * 64;
            if (ACCUM) yp[n] = __fadd_rn(yp[n], r);
            else       yp[n] = r;
        }
    }
}

// ---------------- multi-step LIF (in place, scan over T=4) ----------------
// Y: (4, plane) floats, plane4 = plane/4. v += (x-v)*0.5; s=(v-thr>=0); v*=(1-s)
__global__ __launch_bounds__(256) void lif_kernel(float* __restrict__ Y, int plane4, float thr)
{
    int idx = blockIdx.x * 256 + threadIdx.x;
    if (idx >= plane4) return;
    float4* Yp = (float4*)Y;
    float v0 = 0.f, v1 = 0.f, v2 = 0.f, v3 = 0.f;
    #pragma unroll
    for (int t = 0; t < 4; ++t) {
        float4 xv = Yp[(size_t)t * plane4 + idx];
        v0 = __fadd_rn(v0, __fmul_rn(__fsub_rn(xv.x, v0), 0.5f));
        v1 = __fadd_rn(v1, __fmul_rn(__fsub_rn(xv.y, v1), 0.5f));
        v2 = __fadd_rn(v2, __fmul_rn(__fsub_rn(xv.z, v2), 0.5f));
        v3 = __fadd_rn(v3, __fmul_rn(__fsub_rn(xv.w, v3), 0.5f));
        float s0 = (__fsub_rn(v0, thr) >= 0.f) ? 1.f : 0.f;
        float s1 = (__fsub_rn(v1, thr) >= 0.f) ? 1.f : 0.f;
        float s2 = (__fsub_rn(v2, thr) >= 0.f) ? 1.f : 0.f;
        float s3 = (__fsub_rn(v3, thr) >= 0.f) ? 1.f : 0.f;
        v0 = __fmul_rn(v0, 1.f - s0); v1 = __fmul_rn(v1, 1.f - s1);
        v2 = __fmul_rn(v2, 1.f - s2); v3 = __fmul_rn(v3, 1.f - s3);
        xv.x = s0; xv.y = s1; xv.z = s2; xv.w = s3;
        Yp[(size_t)t * plane4 + idx] = xv;
    }
}

// ---------------- LIF scan + accumulate spikes into global output ----------------
// Yin: chunk-local [4][8][384][196]; Out: global [4][32][384][196]; Out += spikes.
__global__ __launch_bounds__(256) void lif_add_kernel(
    const float* __restrict__ Yin, float* __restrict__ Out, int b0)
{
    const int PL4 = 8 * 384 * 49;      // 150,528 float4 per t
    const int B4  = 384 * 49;          // 18,816 float4 per (t,b)
    int idx = blockIdx.x * 256 + threadIdx.x;
    if (idx >= PL4) return;
    int bl = idx / B4, r = idx - bl * B4;
    const float4* Yp = (const float4*)Yin;
    float v0 = 0.f, v1 = 0.f, v2 = 0.f, v3 = 0.f;
    #pragma unroll
    for (int t = 0; t < 4; ++t) {
        float4 xv = Yp[(size_t)t * PL4 + idx];
        v0 = __fadd_rn(v0, __fmul_rn(__fsub_rn(xv.x, v0), 0.5f));
        v1 = __fadd_rn(v1, __fmul_rn(__fsub_rn(xv.y, v1), 0.5f));
        v2 = __fadd_rn(v2, __fmul_rn(__fsub_rn(xv.z, v2), 0.5f));
        v3 = __fadd_rn(v3, __fmul_rn(__fsub_rn(xv.w, v3), 0.5f));
        float s0 = (__fsub_rn(v0, 1.0f) >= 0.f) ? 1.f : 0.f;
        float s1 = (__fsub_rn(v1, 1.0f) >= 0.f) ? 1.f : 0.f;
        float s2 = (__fsub_rn(v2, 1.0f) >= 0.f) ? 1.f : 0.f;
        float s3 = (__fsub_rn(v3, 1.0f) >= 0.f) ? 1.f : 0.f;
        v0 = __fmul_rn(v0, 1.f - s0); v1 = __fmul_rn(v1, 1.f - s1);
        v2 = __fmul_rn(v2, 1.f - s2); v3 = __fmul_rn(v3, 1.f - s3);
        float4* op = (float4*)Out + ((size_t)(t * 32 + b0 + bl) * B4 + r);
        float4 o = *op;
        o.x = __fadd_rn(o.x, s0); o.y = __fadd_rn(o.y, s1);
        o.z = __fadd_rn(o.z, s2); o.w = __fadd_rn(o.w, s3);
        *op = o;
    }
}

// ---------------- pack 32 head-channels of binary spikes into uint32 ----------------
// S: (TB, 384, 196) spikes; Bits: (TB, 12, 196)
__global__ __launch_bounds__(256) void pack_kernel(const float* __restrict__ S,
                                                   uint32_t* __restrict__ Bits)
{
    int idx = blockIdx.x * 256 + threadIdx.x;
    if (idx >= 4 * 32 * 12 * 196) return;
    int n = idx % 196;
    int rest = idx / 196;
    int h = rest % 12;
    int tb = rest / 12;
    const float* sp = S + ((size_t)tb * 384 + h * 32) * 196 + n;
    uint32_t bits = 0;
    #pragma unroll
    for (int d = 0; d < 32; ++d)
        bits |= (sp[(size_t)d * 196] > 0.5f) ? (1u << d) : 0u;
    Bits[idx] = bits;
}

// ---------------- attention: attn = popc(q&k), policy mask, o = attn*v*0.25 ----------------
// One block per (tb, h). Exact dyadic arithmetic throughout (policy is {0,1}).
__global__ __launch_bounds__(256) void attn_kernel(
    const uint32_t* __restrict__ Qb, const uint32_t* __restrict__ Kb,
    const float* __restrict__ V, const float* __restrict__ P, float* __restrict__ O)
{
    __shared__ uint32_t Qbs[196], Kbs[196];
    __shared__ float Ps[196];
    __shared__ float Vs[32][204];
    __shared__ float Ss[32][204];
    __shared__ float Os[32][36];
    const int tid = threadIdx.x;
    const int bid = blockIdx.x;
    const int tb = bid / 12, h = bid - tb * 12;
    const size_t vbase = ((size_t)tb * 384 + h * 32) * 196;
    const size_t qbase = ((size_t)tb * 12 + h) * 196;
    for (int i = tid; i < 196; i += 256) {
        Qbs[i] = Qb[qbase + i];
        Kbs[i] = Kb[qbase + i];
        Ps[i]  = P[(size_t)tb * 196 + i];
    }
    for (int i = tid; i < 32 * 49; i += 256) {
        int d = i / 49, m4 = i - d * 49;
        *(float4*)&Vs[d][m4 * 4] = *(const float4*)(V + vbase + (size_t)d * 196 + m4 * 4);
    }
    __syncthreads();
    for (int n0 = 0; n0 < 196; n0 += 32) {
        const int rows = min(32, 196 - n0);
        // phase A: scores for 32 query rows x 196 keys (popcount) + policy mask
        for (int idx = tid; idx < rows * 196; idx += 256) {
            int ns = idx / 196, m = idx - ns * 196;
            int n = n0 + ns;
            float s = (float)__popc(Qbs[n] & Kbs[m]);
            float p = Ps[m];
            float e = (m == n) ? 1.f : 0.f;
            Ss[ns][m] = s * (p + (1.f - p) * e);
        }
        __syncthreads();
        // phase B: O-tile (32n x 32d) = Ss(32x196) * Vs^T(196x32), 2x2 per thread
        {
            const int tn = tid & 15, td = tid >> 4;
            float a00 = 0, a01 = 0, a10 = 0, a11 = 0;
            #pragma unroll 7
            for (int m4 = 0; m4 < 49; ++m4) {
                float4 s0 = *(const float4*)&Ss[tn][m4 * 4];
                float4 s1 = *(const float4*)&Ss[tn + 16][m4 * 4];
                float4 u0 = *(const float4*)&Vs[td][m4 * 4];
                float4 u1 = *(const float4*)&Vs[td + 16][m4 * 4];
                a00 += s0.x * u0.x + s0.y * u0.y + s0.z * u0.z + s0.w * u0.w;
                a01 += s0.x * u1.x + s0.y * u1.y + s0.z * u1.z + s0.w * u1.w;
                a10 += s1.x * u0.x + s1.y * u0.y + s1.z * u0.z + s1.w * u0.w;
                a11 += s1.x * u1.x + s1.y * u1.y + s1.z * u1.z + s1.w * u1.w;
            }
            Os[td     ][tn     ] = a00 * 0.25f;
            Os[td + 16][tn     ] = a01 * 0.25f;
            Os[td     ][tn + 16] = a10 * 0.25f;
            Os[td + 16][tn + 16] = a11 * 0.25f;
        }
        __syncthreads();
        // coalesced store of the tile (channel-major, 128B runs)
        {
            const int d = tid >> 3, c4 = tid & 7;
            if (c4 * 4 < rows)
                *(float4*)(O + vbase + (size_t)d * 196 + n0 + c4 * 4) =
                    *(const float4*)&Os[d][c4 * 4];
        }
        __syncthreads();
    }
}

// ---------------- elementwise residual add: Out = A + B ----------------
__global__ __launch_bounds__(256) void add_kernel(const float* __restrict__ A,
    const float* __restrict__ B, float* __restrict__ Out, int n4)
{
    int idx = blockIdx.x * 256 + threadIdx.x;
    if (idx >= n4) return;
    float4 a = ((const float4*)A)[idx];
    float4 b = ((const float4*)B)[idx];
    float4 o;
    o.x = __fadd_rn(a.x, b.x); o.y = __fadd_rn(a.y, b.y);
    o.z = __fadd_rn(a.z, b.z); o.w = __fadd_rn(a.w, b.w);
    ((float4*)Out)[idx] = o;
}

extern "C" void kernel_launch(void* const* d_in, const int* in_sizes, int n_in,
                              void* d_out, int out_size, void* d_ws, size_t ws_size,
                              hipStream_t stream) {
    const float* x   = (const float*)d_in[0];
    const float* pol = (const float*)d_in[1];
    const float* wq = (const float*)d_in[2];
    const float* qg = (const float*)d_in[3];
    const float* qb = (const float*)d_in[4];
    const float* qm = (const float*)d_in[5];
    const float* qv = (const float*)d_in[6];
    const float* wk = (const float*)d_in[7];
    const float* kg = (const float*)d_in[8];
    const float* kb = (const float*)d_in[9];
    const float* km = (const float*)d_in[10];
    const float* kvv= (const float*)d_in[11];
    const float* wv = (const float*)d_in[12];
    const float* vg = (const float*)d_in[13];
    const float* vb = (const float*)d_in[14];
    const float* vm = (const float*)d_in[15];
    const float* vvv= (const float*)d_in[16];
    const float* wp = (const float*)d_in[17];
    const float* bp = (const float*)d_in[18];
    const float* pg = (const float*)d_in[19];
    const float* pb = (const float*)d_in[20];
    const float* pm = (const float*)d_in[21];
    const float* pv = (const float*)d_in[22];
    const float* w1 = (const float*)d_in[23];
    const float* b1 = (const float*)d_in[24];
    const float* g1 = (const float*)d_in[25];
    const float* be1= (const float*)d_in[26];
    const float* m1 = (const float*)d_in[27];
    const float* v1 = (const float*)d_in[28];
    const float* w2 = (const float*)d_in[29];
    const float* b2 = (const float*)d_in[30];
    const float* g2 = (const float*)d_in[31];
    const float* be2= (const float*)d_in[32];
    const float* m2 = (const float*)d_in[33];
    const float* v2 = (const float*)d_in[34];

    // workspace (floats), total 48.2 MiB:
    //   bufA: 9,633,792  (q/k/v/proj spikes; then chunk-local fc1 spike buffer)
    //   bufD: 2,408,448  (chunk-local fc2 conv+bn output, pre-LIF)
    //   bits:   602,112  u32 (Qbits 301,056 + Kbits 301,056)
    // x1 residual lives in d_out; fc2 spikes accumulate into d_out via lif_add.
    float* bufA = (float*)d_ws;
    float* bufD = bufA + 9633792;
    uint32_t* Qbits = (uint32_t*)(bufD + 2408448);
    uint32_t* Kbits = Qbits + 301056;
    float* out = (float*)d_out;

    // q branch: conv+bn, LIF, pack bits; bufA then reused for k
    convbn_kernel<384, false, false><<<dim3(128, 6), 512, 0, stream>>>(x, wq, nullptr, qg, qb, qm, qv, bufA, 384, 32, 0, 0, 0);
    lif_kernel<<<2352, 256, 0, stream>>>(bufA, 602112, 1.0f);
    pack_kernel<<<1176, 256, 0, stream>>>(bufA, Qbits);
    // k branch
    convbn_kernel<384, false, false><<<dim3(128, 6), 512, 0, stream>>>(x, wk, nullptr, kg, kb, km, kvv, bufA, 384, 32, 0, 0, 0);
    lif_kernel<<<2352, 256, 0, stream>>>(bufA, 602112, 1.0f);
    pack_kernel<<<1176, 256, 0, stream>>>(bufA, Kbits);
    // v branch (spikes stay as floats in bufA)
    convbn_kernel<384, false, false><<<dim3(128, 6), 512, 0, stream>>>(x, wv, nullptr, vg, vb, vm, vvv, bufA, 384, 32, 0, 0, 0);
    lif_kernel<<<2352, 256, 0, stream>>>(bufA, 602112, 1.0f);

    // attention (exact popcount) -> d_out, then attn LIF (thr=0.5) in place
    attn_kernel<<<1536, 256, 0, stream>>>(Qbits, Kbits, bufA, pol, out);
    lif_kernel<<<2352, 256, 0, stream>>>(out, 602112, 0.5f);

    // projection conv+bn+LIF (binary input -> fma exact); residual 1: out = x + proj
    convbn_kernel<384, true, false><<<dim3(128, 6), 512, 0, stream>>>(out, wp, bp, pg, pb, pm, pv, bufA, 384, 32, 0, 0, 0);
    lif_kernel<<<2352, 256, 0, stream>>>(bufA, 602112, 1.0f);
    add_kernel<<<9408, 256, 0, stream>>>(x, bufA, out, 2408448);   // out = x1

    // MLP chunked over b in groups of 8 (LIF recurrence over t preserved):
    //   fc1: out (global, continuous) -> bufA chunk-local; LIF;
    //   fc2: bufA (binary -> fma exact) -> bufD chunk-local (pre-LIF);
    //   lif_add: T-scan spikes of bufD accumulated into out (= x1 + h).
    // Chunk c touches out rows b in [8c, 8c+8) only, never re-read by later fc1.
    for (int c = 0; c < 4; ++c) {
        convbn_kernel<384, false, false><<<dim3(32, 24), 512, 0, stream>>>(out, w1, b1, g1, be1, m1, v1, bufA, 1536, 8, c * 8, 0, 1);
        lif_kernel<<<2352, 256, 0, stream>>>(bufA, 602112, 1.0f);
        convbn_kernel<1536, true, false><<<dim3(32, 6), 512, 0, stream>>>(bufA, w2, b2, g2, be2, m2, v2, bufD, 384, 8, c * 8, 1, 1);
        lif_add_kernel<<<588, 256, 0, stream>>>(bufD, out, c * 8);
    }
}

// Round 5
// 2249.094 us; speedup vs baseline: 1.0153x; 1.0153x over previous
//
#include <hip/hip_runtime.h>
#include <cstdint>
#include <cstddef>

#define N_POS 196

// async global->LDS DMA, 16B per lane; lds dest must be wave-uniform base (+lane*16)
__device__ __forceinline__ void async_copy16(const float* g, float* l) {
    __builtin_amdgcn_global_load_lds(
        (const __attribute__((address_space(1))) uint32_t*)g,
        (__attribute__((address_space(3))) uint32_t*)l,
        16, 0, 0);
}

// ---------------- 1x1 conv (channel matmul) + folded BatchNorm ----------------
// X: (ntb, CIN, 196)  W: (Cout, CIN)  Y: (ntb, Cout, 196)
// Per block: one tb, 64 output channels, all 196 positions.
// K pipelined in 16-row chunks, double-buffered, X staged via global_load_lds DMA.
// Reduction order: k ascending, sequential per output — bitwise-stable (matches np).
// USE_FMA=false: separate __fmul_rn/__fadd_rn (continuous inputs, matches np einsum).
// USE_FMA=true: fmaf — bitwise identical for binary {0,1} inputs. ACCUM: Y += result.
template<int CIN, bool USE_FMA, bool ACCUM>
__global__ __launch_bounds__(512) void convbn_kernel(
    const float* __restrict__ X, const float* __restrict__ W,
    const float* __restrict__ Bi, const float* __restrict__ Ga,
    const float* __restrict__ Be, const float* __restrict__ Mu,
    const float* __restrict__ Va, float* __restrict__ Y, int Cout,
    int nb, int b0, int xlocal, int ylocal)
{
    constexpr int NCH = CIN / 16;
    // layout: Xs[2][16*196] floats, then Ws[2][16*64] floats  (33280 B total)
    __shared__ float lds[2 * 3136 + 2 * 1024];
    float* Xs = lds;
    float* Ws = lds + 6272;
    const int tid = threadIdx.x;
    const int l   = blockIdx.x;
    const int t   = l / nb;
    const int bl  = l - t * nb;
    const int tbg = t * 32 + b0 + bl;
    const int xtb = xlocal ? l : tbg;
    const int ytb = ylocal ? l : tbg;
    const int o0  = blockIdx.y * 64;
    const int n0  = tid & 63;                 // position within 64-chunk
    const int obase = (tid >> 6) * 8;         // 8 consecutive outputs per thread
    const int col3 = (n0 < 4) ? (n0 + 192) : 196;  // n0>=4 reads dead (in-bounds) data
    const float* Xtb = X + (size_t)xtb * CIN * N_POS;
    const float* Wp  = W + (size_t)o0 * CIN;

    float acc[8][4];
    #pragma unroll
    for (int i = 0; i < 8; ++i)
        #pragma unroll
        for (int j = 0; j < 4; ++j) acc[i][j] = 0.f;

    // stage chunk kc..kc+15 into buffer buf: W prefetch->VGPR first, then X DMA,
    // then W ds_writes (compiler waits only the W load, X DMAs stay in flight)
    auto stage = [&](int buf, int kc) {
        const int oo = tid >> 3, k2 = (tid & 7) * 2;
        float2 wv2 = *(const float2*)(Wp + (size_t)oo * CIN + kc + k2);
        {   // X: 16 rows x 196 floats = 784 float4, linear in LDS
            int i = tid;
            const float* g = Xtb + (size_t)(kc + i / 49) * N_POS + (i % 49) * 4;
            async_copy16(g, &Xs[buf * 3136 + (i & ~63) * 4]);
        }
        if (tid < 272) {
            int i = tid + 512;
            const float* g = Xtb + (size_t)(kc + i / 49) * N_POS + (i % 49) * 4;
            async_copy16(g, &Xs[buf * 3136 + (i & ~63) * 4]);
        }
        Ws[buf * 1024 + k2 * 64 + oo]       = wv2.x;
        Ws[buf * 1024 + (k2 + 1) * 64 + oo] = wv2.y;
    };

    stage(0, 0);
    __syncthreads();            // implicit vmcnt(0): prologue DMA complete

    int buf = 0;
    for (int ch = 0; ch < NCH; ++ch) {
        if (ch + 1 < NCH) stage(buf ^ 1, (ch + 1) * 16);
        const float* Xb = Xs + buf * 3136;
        const float* Wb = Ws + buf * 1024;
        #pragma unroll 4
        for (int kk = 0; kk < 16; ++kk) {
            float4 wA = *(const float4*)(Wb + kk * 64 + obase);      // wave-uniform bcast
            float4 wB = *(const float4*)(Wb + kk * 64 + obase + 4);
            float xv[4] = { Xb[kk * 196 + n0], Xb[kk * 196 + n0 + 64],
                            Xb[kk * 196 + n0 + 128], Xb[kk * 196 + col3] };
            float wv[8] = { wA.x, wA.y, wA.z, wA.w, wB.x, wB.y, wB.z, wB.w };
            #pragma unroll
            for (int i = 0; i < 8; ++i)
                #pragma unroll
                for (int j = 0; j < 4; ++j) {
                    if (USE_FMA) acc[i][j] = fmaf(wv[i], xv[j], acc[i][j]);
                    else         acc[i][j] = __fadd_rn(acc[i][j], __fmul_rn(wv[i], xv[j]));
                }
        }
        __syncthreads();        // drains next chunk's DMA; protects buf reuse
        buf ^= 1;
    }

    #pragma unroll
    for (int i = 0; i < 8; ++i) {
        int o = o0 + obase + i;
        // match reference op-for-op: inv = g*rsqrt(var+eps); y = conv (+ bias);
        // r = y*inv + (beta - m*inv)
        float sc = __fmul_rn(Ga[o], 1.0f / sqrtf(__fadd_rn(Va[o], 1e-5f)));
        float sh = __fsub_rn(Be[o], __fmul_rn(Mu[o], sc));
        float* yp = Y + ((size_t)ytb * Cout + o) * N_POS;
        #pragma unroll
        for (int j = 0; j < 4; ++j) {
            if (j == 3 && n0 >= 4) continue;
            float y = acc[i][j];
            if (Bi) y = __fadd_rn(y, Bi[o]);
            float r = __fadd_rn(__fmul_rn(y, sc), sh);
            int n = n0 + j * 64;
            if (ACCUM) yp[n] = __fadd_rn(yp[n], r);
            else       yp[n] = r;
        }
    }
}

// ---------------- multi-step LIF (in place, scan over T=4) ----------------
// Y: (4, plane) floats, plane4 = plane/4. v += (x-v)*0.5; s=(v-thr>=0); v*=(1-s)
__global__ __launch_bounds__(256) void lif_kernel(float* __restrict__ Y, int plane4, float thr)
{
    int idx = blockIdx.x * 256 + threadIdx.x;
    if (idx >= plane4) return;
    float4* Yp = (float4*)Y;
    float v0 = 0.f, v1 = 0.f, v2 = 0.f, v3 = 0.f;
    #pragma unroll
    for (int t = 0; t < 4; ++t) {
        float4 xv = Yp[(size_t)t * plane4 + idx];
        v0 = __fadd_rn(v0, __fmul_rn(__fsub_rn(xv.x, v0), 0.5f));
        v1 = __fadd_rn(v1, __fmul_rn(__fsub_rn(xv.y, v1), 0.5f));
        v2 = __fadd_rn(v2, __fmul_rn(__fsub_rn(xv.z, v2), 0.5f));
        v3 = __fadd_rn(v3, __fmul_rn(__fsub_rn(xv.w, v3), 0.5f));
        float s0 = (__fsub_rn(v0, thr) >= 0.f) ? 1.f : 0.f;
        float s1 = (__fsub_rn(v1, thr) >= 0.f) ? 1.f : 0.f;
        float s2 = (__fsub_rn(v2, thr) >= 0.f) ? 1.f : 0.f;
        float s3 = (__fsub_rn(v3, thr) >= 0.f) ? 1.f : 0.f;
        v0 = __fmul_rn(v0, 1.f - s0); v1 = __fmul_rn(v1, 1.f - s1);
        v2 = __fmul_rn(v2, 1.f - s2); v3 = __fmul_rn(v3, 1.f - s3);
        xv.x = s0; xv.y = s1; xv.z = s2; xv.w = s3;
        Yp[(size_t)t * plane4 + idx] = xv;
    }
}

// ---------------- LIF scan + accumulate spikes into global output ----------------
// Yin: chunk-local [4][8][384][196]; Out: global [4][32][384][196]; Out += spikes.
__global__ __launch_bounds__(256) void lif_add_kernel(
    const float* __restrict__ Yin, float* __restrict__ Out, int b0)
{
    const int PL4 = 8 * 384 * 49;      // 150,528 float4 per t
    const int B4  = 384 * 49;          // 18,816 float4 per (t,b)
    int idx = blockIdx.x * 256 + threadIdx.x;
    if (idx >= PL4) return;
    int bl = idx / B4, r = idx - bl * B4;
    const float4* Yp = (const float4*)Yin;
    float v0 = 0.f, v1 = 0.f, v2 = 0.f, v3 = 0.f;
    #pragma unroll
    for (int t = 0; t < 4; ++t) {
        float4 xv = Yp[(size_t)t * PL4 + idx];
        v0 = __fadd_rn(v0, __fmul_rn(__fsub_rn(xv.x, v0), 0.5f));
        v1 = __fadd_rn(v1, __fmul_rn(__fsub_rn(xv.y, v1), 0.5f));
        v2 = __fadd_rn(v2, __fmul_rn(__fsub_rn(xv.z, v2), 0.5f));
        v3 = __fadd_rn(v3, __fmul_rn(__fsub_rn(xv.w, v3), 0.5f));
        float s0 = (__fsub_rn(v0, 1.0f) >= 0.f) ? 1.f : 0.f;
        float s1 = (__fsub_rn(v1, 1.0f) >= 0.f) ? 1.f : 0.f;
        float s2 = (__fsub_rn(v2, 1.0f) >= 0.f) ? 1.f : 0.f;
        float s3 = (__fsub_rn(v3, 1.0f) >= 0.f) ? 1.f : 0.f;
        v0 = __fmul_rn(v0, 1.f - s0); v1 = __fmul_rn(v1, 1.f - s1);
        v2 = __fmul_rn(v2, 1.f - s2); v3 = __fmul_rn(v3, 1.f - s3);
        float4* op = (float4*)Out + ((size_t)(t * 32 + b0 + bl) * B4 + r);
        float4 o = *op;
        o.x = __fadd_rn(o.x, s0); o.y = __fadd_rn(o.y, s1);
        o.z = __fadd_rn(o.z, s2); o.w = __fadd_rn(o.w, s3);
        *op = o;
    }
}

// ---------------- pack 32 head-channels of binary spikes into uint32 ----------------
// S: (TB, 384, 196) spikes; Bits: (TB, 12, 196)
__global__ __launch_bounds__(256) void pack_kernel(const float* __restrict__ S,
                                                   uint32_t* __restrict__ Bits)
{
    int idx = blockIdx.x * 256 + threadIdx.x;
    if (idx >= 4 * 32 * 12 * 196) return;
    int n = idx % 196;
    int rest = idx / 196;
    int h = rest % 12;
    int tb = rest / 12;
    const float* sp = S + ((size_t)tb * 384 + h * 32) * 196 + n;
    uint32_t bits = 0;
    #pragma unroll
    for (int d = 0; d < 32; ++d)
        bits |= (sp[(size_t)d * 196] > 0.5f) ? (1u << d) : 0u;
    Bits[idx] = bits;
}

// ---------------- attention: attn = popc(q&k), policy mask, o = attn*v*0.25 ----------------
// One block per (tb, h). Exact dyadic arithmetic throughout (policy is {0,1}).
__global__ __launch_bounds__(256) void attn_kernel(
    const uint32_t* __restrict__ Qb, const uint32_t* __restrict__ Kb,
    const float* __restrict__ V, const float* __restrict__ P, float* __restrict__ O)
{
    __shared__ uint32_t Qbs[196], Kbs[196];
    __shared__ float Ps[196];
    __shared__ float Vs[32][204];
    __shared__ float Ss[32][204];
    __shared__ float Os[32][36];
    const int tid = threadIdx.x;
    const int bid = blockIdx.x;
    const int tb = bid / 12, h = bid - tb * 12;
    const size_t vbase = ((size_t)tb * 384 + h * 32) * 196;
    const size_t qbase = ((size_t)tb * 12 + h) * 196;
    for (int i = tid; i < 196; i += 256) {
        Qbs[i] = Qb[qbase + i];
        Kbs[i] = Kb[qbase + i];
        Ps[i]  = P[(size_t)tb * 196 + i];
    }
    for (int i = tid; i < 32 * 49; i += 256) {
        int d = i / 49, m4 = i - d * 49;
        *(float4*)&Vs[d][m4 * 4] = *(const float4*)(V + vbase + (size_t)d * 196 + m4 * 4);
    }
    __syncthreads();
    for (int n0 = 0; n0 < 196; n0 += 32) {
        const int rows = min(32, 196 - n0);
        // phase A: scores for 32 query rows x 196 keys (popcount) + policy mask
        for (int idx = tid; idx < rows * 196; idx += 256) {
            int ns = idx / 196, m = idx - ns * 196;
            int n = n0 + ns;
            float s = (float)__popc(Qbs[n] & Kbs[m]);
            float p = Ps[m];
            float e = (m == n) ? 1.f : 0.f;
            Ss[ns][m] = s * (p + (1.f - p) * e);
        }
        __syncthreads();
        // phase B: O-tile (32n x 32d) = Ss(32x196) * Vs^T(196x32), 2x2 per thread
        {
            const int tn = tid & 15, td = tid >> 4;
            float a00 = 0, a01 = 0, a10 = 0, a11 = 0;
            #pragma unroll 7
            for (int m4 = 0; m4 < 49; ++m4) {
                float4 s0 = *(const float4*)&Ss[tn][m4 * 4];
                float4 s1 = *(const float4*)&Ss[tn + 16][m4 * 4];
                float4 u0 = *(const float4*)&Vs[td][m4 * 4];
                float4 u1 = *(const float4*)&Vs[td + 16][m4 * 4];
                a00 += s0.x * u0.x + s0.y * u0.y + s0.z * u0.z + s0.w * u0.w;
                a01 += s0.x * u1.x + s0.y * u1.y + s0.z * u1.z + s0.w * u1.w;
                a10 += s1.x * u0.x + s1.y * u0.y + s1.z * u0.z + s1.w * u0.w;
                a11 += s1.x * u1.x + s1.y * u1.y + s1.z * u1.z + s1.w * u1.w;
            }
            Os[td     ][tn     ] = a00 * 0.25f;
            Os[td + 16][tn     ] = a01 * 0.25f;
            Os[td     ][tn + 16] = a10 * 0.25f;
            Os[td + 16][tn + 16] = a11 * 0.25f;
        }
        __syncthreads();
        // coalesced store of the tile (channel-major, 128B runs)
        {
            const int d = tid >> 3, c4 = tid & 7;
            if (c4 * 4 < rows)
                *(float4*)(O + vbase + (size_t)d * 196 + n0 + c4 * 4) =
                    *(const float4*)&Os[d][c4 * 4];
        }
        __syncthreads();
    }
}

// ---------------- elementwise residual add: Out = A + B ----------------
__global__ __launch_bounds__(256) void add_kernel(const float* __restrict__ A,
    const float* __restrict__ B, float* __restrict__ Out, int n4)
{
    int idx = blockIdx.x * 256 + threadIdx.x;
    if (idx >= n4) return;
    float4 a = ((const float4*)A)[idx];
    float4 b = ((const float4*)B)[idx];
    float4 o;
    o.x = __fadd_rn(a.x, b.x); o.y = __fadd_rn(a.y, b.y);
    o.z = __fadd_rn(a.z, b.z); o.w = __fadd_rn(a.w, b.w);
    ((float4*)Out)[idx] = o;
}

extern "C" void kernel_launch(void* const* d_in, const int* in_sizes, int n_in,
                              void* d_out, int out_size, void* d_ws, size_t ws_size,
                              hipStream_t stream) {
    const float* x   = (const float*)d_in[0];
    const float* pol = (const float*)d_in[1];
    const float* wq = (const float*)d_in[2];
    const float* qg = (const float*)d_in[3];
    const float* qb = (const float*)d_in[4];
    const float* qm = (const float*)d_in[5];
    const float* qv = (const float*)d_in[6];
    const float* wk = (const float*)d_in[7];
    const float* kg = (const float*)d_in[8];
    const float* kb = (const float*)d_in[9];
    const float* km = (const float*)d_in[10];
    const float* kvv= (const float*)d_in[11];
    const float* wv = (const float*)d_in[12];
    const float* vg = (const float*)d_in[13];
    const float* vb = (const float*)d_in[14];
    const float* vm = (const float*)d_in[15];
    const float* vvv= (const float*)d_in[16];
    const float* wp = (const float*)d_in[17];
    const float* bp = (const float*)d_in[18];
    const float* pg = (const float*)d_in[19];
    const float* pb = (const float*)d_in[20];
    const float* pm = (const float*)d_in[21];
    const float* pv = (const float*)d_in[22];
    const float* w1 = (const float*)d_in[23];
    const float* b1 = (const float*)d_in[24];
    const float* g1 = (const float*)d_in[25];
    const float* be1= (const float*)d_in[26];
    const float* m1 = (const float*)d_in[27];
    const float* v1 = (const float*)d_in[28];
    const float* w2 = (const float*)d_in[29];
    const float* b2 = (const float*)d_in[30];
    const float* g2 = (const float*)d_in[31];
    const float* be2= (const float*)d_in[32];
    const float* m2 = (const float*)d_in[33];
    const float* v2 = (const float*)d_in[34];

    // workspace (floats), total 48.2 MiB:
    //   bufA: 9,633,792  (q/k/v/proj spikes; then chunk-local fc1 spike buffer)
    //   bufD: 2,408,448  (chunk-local fc2 conv+bn output, pre-LIF)
    //   bits:   602,112  u32 (Qbits 301,056 + Kbits 301,056)
    float* bufA = (float*)d_ws;
    float* bufD = bufA + 9633792;
    uint32_t* Qbits = (uint32_t*)(bufD + 2408448);
    uint32_t* Kbits = Qbits + 301056;
    float* out = (float*)d_out;

    // q branch: conv+bn, LIF, pack bits; bufA then reused for k
    convbn_kernel<384, false, false><<<dim3(128, 6), 512, 0, stream>>>(x, wq, nullptr, qg, qb, qm, qv, bufA, 384, 32, 0, 0, 0);
    lif_kernel<<<2352, 256, 0, stream>>>(bufA, 602112, 1.0f);
    pack_kernel<<<1176, 256, 0, stream>>>(bufA, Qbits);
    // k branch
    convbn_kernel<384, false, false><<<dim3(128, 6), 512, 0, stream>>>(x, wk, nullptr, kg, kb, km, kvv, bufA, 384, 32, 0, 0, 0);
    lif_kernel<<<2352, 256, 0, stream>>>(bufA, 602112, 1.0f);
    pack_kernel<<<1176, 256, 0, stream>>>(bufA, Kbits);
    // v branch (spikes stay as floats in bufA)
    convbn_kernel<384, false, false><<<dim3(128, 6), 512, 0, stream>>>(x, wv, nullptr, vg, vb, vm, vvv, bufA, 384, 32, 0, 0, 0);
    lif_kernel<<<2352, 256, 0, stream>>>(bufA, 602112, 1.0f);

    // attention (exact popcount) -> d_out, then attn LIF (thr=0.5) in place
    attn_kernel<<<1536, 256, 0, stream>>>(Qbits, Kbits, bufA, pol, out);
    lif_kernel<<<2352, 256, 0, stream>>>(out, 602112, 0.5f);

    // projection conv+bn+LIF (binary input -> fma exact); residual 1: out = x + proj
    convbn_kernel<384, true, false><<<dim3(128, 6), 512, 0, stream>>>(out, wp, bp, pg, pb, pm, pv, bufA, 384, 32, 0, 0, 0);
    lif_kernel<<<2352, 256, 0, stream>>>(bufA, 602112, 1.0f);
    add_kernel<<<9408, 256, 0, stream>>>(x, bufA, out, 2408448);   // out = x1

    // MLP chunked over b in groups of 8 (LIF recurrence over t preserved):
    //   fc1: out (global, continuous) -> bufA chunk-local; LIF;
    //   fc2: bufA (binary -> fma exact) -> bufD chunk-local (pre-LIF);
    //   lif_add: T-scan spikes of bufD accumulated into out (= x1 + h).
    // Chunk c touches out rows b in [8c, 8c+8) only, never re-read by later fc1.
    for (int c = 0; c < 4; ++c) {
        convbn_kernel<384, false, false><<<dim3(32, 24), 512, 0, stream>>>(out, w1, b1, g1, be1, m1, v1, bufA, 1536, 8, c * 8, 0, 1);
        lif_kernel<<<2352, 256, 0, stream>>>(bufA, 602112, 1.0f);
        convbn_kernel<1536, true, false><<<dim3(32, 6), 512, 0, stream>>>(bufA, w2, b2, g2, be2, m2, v2, bufD, 384, 8, c * 8, 1, 1);
        lif_add_kernel<<<588, 256, 0, stream>>>(bufD, out, c * 8);
    }
}